// Round 15
// baseline (168.418 us; speedup 1.0000x reference)
//
#include <hip/hip_runtime.h>
#include <hip/hip_bf16.h>

typedef short short8 __attribute__((ext_vector_type(8)));
typedef float float4v __attribute__((ext_vector_type(4)));

#define NIMG 32
#define CIN 256
#define COUT 256
#define HH 56
#define WW 56
#define HP 58
#define WP 58
#define PIXIMG (HH * WW)          /* 3136 */
#define TOTPIX (NIMG * PIXIMG)    /* 100352 */
#define OUTSTRIDE_N (COUT * PIXIMG)
#define TR_BLOCKS (NIMG * HP * 4) /* 7424 transpose blocks in k_pre */

static constexpr size_t XT_ELEMS = (size_t)NIMG * HP * WP * CIN; // bf16
static constexpr size_t WT_ELEMS = (size_t)9 * COUT * CIN;       // bf16

// fp32 -> bf16 bits, round-to-nearest-even (finite inputs only)
static __device__ __forceinline__ unsigned short f2bf(float f) {
    unsigned int u = __builtin_bit_cast(unsigned int, f);
    u = (u + 0x7fffu + ((u >> 16) & 1u)) >> 16;
    return (unsigned short)u;
}

// async global(16B/lane) -> LDS (wave-uniform base + lane*16)
static __device__ __forceinline__ void gl16(const unsigned short* g, const char* l) {
    __builtin_amdgcn_global_load_lds(
        (const __attribute__((address_space(1))) void*)g,
        (__attribute__((address_space(3))) void*)l, 16, 0, 0);
}

// ---------------------------------------------------------------------------
// Merged pre-pass (unchanged, at HBM roofline). Blocks [0, TR_BLOCKS):
// NCHW fp32 -> x_t[n][h'][w'][ic] bf16 padded, halo zeroed.
// Blocks [TR_BLOCKS, +256): wt[tap][oc][ic] = bf16(weight*mask).
// ---------------------------------------------------------------------------
__global__ __launch_bounds__(256) void k_pre(const float* __restrict__ x,
                                             const float* __restrict__ wgt,
                                             const float* __restrict__ msk,
                                             unsigned short* __restrict__ xt,
                                             unsigned short* __restrict__ wt) {
    int t = threadIdx.x;
    if (blockIdx.x >= TR_BLOCKS) {
        int g = (blockIdx.x - TR_BLOCKS) * 256 + t; // g = oc*256 + ic
        const float* wp = wgt + (size_t)g * 9;
        const float* mp = msk + (size_t)g * 9;
#pragma unroll
        for (int tap = 0; tap < 9; ++tap)
            wt[(size_t)tap * (COUT * CIN) + g] = f2bf(wp[tap] * mp[tap]);
        return;
    }
    int b   = blockIdx.x;
    int icb = b & 3;
    int hp  = (b >> 2) % HP;    // padded output row 0..57
    int n   = b / (4 * HP);
    unsigned short* rowb = xt + ((size_t)(n * HP + hp) * WP) * CIN + icb * 64;

    if (hp == 0 || hp == HP - 1) {
        for (int idx = t; idx < WP * 8; idx += 256) {
            int wq = idx >> 3, q = idx & 7;
            *(uint4*)(rowb + (size_t)wq * CIN + q * 8) = (uint4){0, 0, 0, 0};
        }
        return;
    }
    int h = hp - 1;
    __shared__ __align__(16) char lds[64 * 128]; // [w 64][ic 64] bf16, swizzled
    int w = t & 63, icl0 = t >> 6;
    if (w < WW) {
        const float* src = x + ((size_t)(n * CIN + icb * 64 + icl0) * HH + h) * WW + w;
#pragma unroll
        for (int j = 0; j < 16; ++j) {
            float v = src[(size_t)(j * 4) * PIXIMG];
            int icl = icl0 + j * 4;
            *(unsigned short*)(lds + w * 128 + ((icl * 2) ^ ((w & 7) << 4))) = f2bf(v);
        }
    }
    __syncthreads();
    int ic4 = t & 15, wr = t >> 4;
    unsigned short* dst = rowb + (size_t)CIN + ic4 * 4; // w'=1 base
#pragma unroll
    for (int p = 0; p < 4; ++p) {
        int w2 = wr + p * 16;
        if (w2 < WW) {
            uint2 v = *(const uint2*)(lds + w2 * 128 + ((ic4 * 8) ^ ((w2 & 7) << 4)));
            *(uint2*)(dst + (size_t)w2 * CIN) = v;
        }
    }
    if (t < 32) { // zero w'=0 and w'=57 columns
        int col = (t >> 4) * (WP - 1);
        *(uint2*)(rowb + (size_t)col * CIN + (t & 15) * 4) = (uint2){0, 0};
    }
}

// ---------------------------------------------------------------------------
// Main conv, round-15: SAME drain structure + 12 waves/CU as the champion,
// but 2-wave blocks (128 thr), tile 128 oc x 64 pix, LDS 24KB -> 6 blocks/CU
// = 6 INDEPENDENT BARRIER DOMAINS (vs champion's 3). The diagnosed bottleneck
// is the per-step vmcnt(0)+barrier drain that stalls ALL waves of a block at
// once; only other blocks hide it. The one positive lever in 14 rounds was
// more domains (2->3, r2->r5 +13%); this pushes 3->6 at constant TLP.
// Accepted costs (mechanisms falsified as bottlenecks): A staged 2x chip-wide
// (L2-hot, r11/r13: fetch volume irrelevant), LDS traffic +17% (r13: LDS BW
// not binding), 12 gl16/thread vs 8.
// ---------------------------------------------------------------------------
__global__ __launch_bounds__(128, 3) void k_conv(const unsigned short* __restrict__ xt,
                                                 const unsigned short* __restrict__ wt,
                                                 float* __restrict__ out) {
    __shared__ __align__(16) char lds[24576];
    // A [128 oc][64 ic] bf16 @0 (16KB), B [64 pix][64 ic] @16384 (8KB);
    // epilogue aliases as float ep[64][68] (17408B).

    const int t    = threadIdx.x;
    const int lane = t & 63;
    const int wid  = t >> 6;   // 0..1: wave owns oc rows [wid*64, +64)

    // bijective XCD swizzle: 3136 blocks = 8 XCDs x 392
    const int b0 = blockIdx.x;
    const int b  = (b0 & 7) * 392 + (b0 >> 3);
    const int ptile = b >> 1;  // 1568 pixel tiles of 64
    const int ocb   = b & 1;   // 128-oc half

    // ---- staging addressing (pre-swizzled global src, linear LDS dest) ----
    const int rl = lane >> 3;                  // row-within-8 at dest
    const int sc = ((lane & 7) ^ rl) * 8;      // inverse-swizzled src col (elems)
    // A: wave wid stages rows [wid*64, +64) as 8 chunks of 8 rows
    const unsigned short* aSrc = wt + (size_t)(ocb * 128 + wid * 64 + rl) * CIN + sc;
    char* const ldsA = lds + (wid * 64) * 128;
    // B: wave wid stages rows [wid*32, +32) as 4 chunks of 8 rows
    const unsigned short* bS[4];
#pragma unroll
    for (int c = 0; c < 4; ++c) {
        int r   = wid * 32 + c * 8 + rl;
        int pg  = ptile * 64 + r;
        int n   = pg / PIXIMG;
        int rem = pg - n * PIXIMG;
        int h   = rem / WW, w = rem - h * WW;
        bS[c] = xt + ((size_t)((n * HP + h) * WP + w)) * CIN + sc;
    }
    char* const ldsB = lds + 16384 + (wid * 32) * 128;

    // ---- fragment read offsets ----
    const int l15  = lane & 15;
    const int lg   = lane >> 4;
    const int swzf = (lane & 7) << 4;
    int colk[2];
    colk[0] = (lg * 16) ^ swzf;
    colk[1] = (64 + lg * 16) ^ swzf;
    int rowA[4], rowB[4];
#pragma unroll
    for (int i = 0; i < 4; ++i) {
        rowA[i] = (wid * 64 + i * 16 + l15) * 128;
        rowB[i] = 16384 + (i * 16 + l15) * 128;
    }

    float4v acc[4][4];
#pragma unroll
    for (int i = 0; i < 4; ++i)
#pragma unroll
        for (int j = 0; j < 4; ++j)
            acc[i][j] = (float4v){0.f, 0.f, 0.f, 0.f};

    // ---- main loop: 36 K-steps, single-buffered drain (champion schedule) ----
#pragma unroll 1
    for (int s = 0; s < 36; ++s) {
        const int tap = s >> 2;
        const int dh  = (tap * 86) >> 8;
        const int dw  = tap - dh * 3;
        const size_t ao = (size_t)tap * (COUT * CIN) + (size_t)((s & 3) << 6);
        const size_t bo = (size_t)(dh * WP + dw) * CIN + (size_t)((s & 3) << 6);
#pragma unroll
        for (int c = 0; c < 8; ++c) gl16(aSrc + ao + c * (8 * CIN), ldsA + c * 1024);
#pragma unroll
        for (int c = 0; c < 4; ++c) gl16(bS[c] + bo, ldsB + c * 1024);
        __syncthreads(); // vmcnt(0) drain + barrier: buffer ready
#pragma unroll
        for (int kk = 0; kk < 2; ++kk) {
            short8 af[4], bfr[4];
#pragma unroll
            for (int i = 0; i < 4; ++i)
                af[i] = *(const short8*)(lds + rowA[i] + colk[kk]);
#pragma unroll
            for (int i = 0; i < 4; ++i)
                bfr[i] = *(const short8*)(lds + rowB[i] + colk[kk]);
#pragma unroll
            for (int oi = 0; oi < 4; ++oi)
#pragma unroll
                for (int pi = 0; pi < 4; ++pi)
                    acc[oi][pi] = __builtin_amdgcn_mfma_f32_16x16x32_bf16(
                        af[oi], bfr[pi], acc[oi][pi], 0, 0, 0);
        }
        __syncthreads(); // reads retired before next stage overwrites
    }

    // ---- epilogue: 2 chunks of 64 oc via LDS transpose, coalesced stores ----
    float* ep = (float*)lds; // [64 oc][68] f32, pad kills write conflicts
#pragma unroll 1
    for (int c = 0; c < 2; ++c) {
        if (wid == c) {
#pragma unroll
            for (int oi = 0; oi < 4; ++oi)
#pragma unroll
                for (int pi = 0; pi < 4; ++pi)
#pragma unroll
                    for (int r = 0; r < 4; ++r)
                        ep[(oi * 16 + lg * 4 + r) * 68 + (pi * 16 + l15)] =
                            acc[oi][pi][r];
        }
        __syncthreads();
        const int erow = t >> 4;        // 0..7
        const int ecol = (t & 15) * 4;  // 0..60
        int pg  = ptile * 64 + ecol;
        int n2  = pg / PIXIMG;
        int rem = pg - n2 * PIXIMG;     // 3136%4==0: float4 stays in-image
        float* ob = out + (size_t)n2 * OUTSTRIDE_N +
                    (size_t)(ocb * 128 + c * 64) * PIXIMG + rem;
#pragma unroll
        for (int p = 0; p < 8; ++p) {
            int row = p * 8 + erow;     // 0..63
            float4v v = *(const float4v*)&ep[row * 68 + ecol];
            *(float4v*)(ob + (size_t)row * PIXIMG) = v;
        }
        __syncthreads(); // chunk reads done before next chunk's writes
    }
}

// ---------------------------------------------------------------------------
// Fallback (ws too small): direct fp32 conv, slow but correct
// ---------------------------------------------------------------------------
__global__ __launch_bounds__(256) void k_naive(const float* __restrict__ x,
                                               const float* __restrict__ wg,
                                               const float* __restrict__ mk,
                                               float* __restrict__ out, int total) {
    int idx = blockIdx.x * 256 + threadIdx.x;
    if (idx >= total) return;
    int w  = idx % WW;
    int h  = (idx / WW) % HH;
    int oc = (idx / PIXIMG) % COUT;
    int n  = idx / (COUT * PIXIMG);
    float s = 0.f;
    for (int ic = 0; ic < CIN; ++ic) {
        const float* xp = x + (size_t)(n * CIN + ic) * PIXIMG;
        const float* wp = wg + (size_t)(oc * CIN + ic) * 9;
        const float* mp = mk + (size_t)(oc * CIN + ic) * 9;
#pragma unroll
        for (int kh = 0; kh < 3; ++kh) {
            int hy = h + kh - 1;
            if ((unsigned)hy >= HH) continue;
#pragma unroll
            for (int kw = 0; kw < 3; ++kw) {
                int wx = w + kw - 1;
                if ((unsigned)wx >= WW) continue;
                s += xp[hy * WW + wx] * wp[kh * 3 + kw] * mp[kh * 3 + kw];
            }
        }
    }
    out[idx] = s;
}

extern "C" void kernel_launch(void* const* d_in, const int* in_sizes, int n_in,
                              void* d_out, int out_size, void* d_ws, size_t ws_size,
                              hipStream_t stream) {
    const float* x  = (const float*)d_in[0];
    const float* wg = (const float*)d_in[1];
    const float* mk = (const float*)d_in[2];
    float* out = (float*)d_out;

    size_t need = XT_ELEMS * 2 + WT_ELEMS * 2 + 256;
    if (ws_size < need) {
        int total = NIMG * COUT * PIXIMG;
        k_naive<<<(total + 255) / 256, 256, 0, stream>>>(x, wg, mk, out, total);
        return;
    }

    unsigned short* xt = (unsigned short*)d_ws;
    unsigned short* wt = (unsigned short*)((char*)d_ws + XT_ELEMS * 2);

    k_pre<<<TR_BLOCKS + (COUT * CIN) / 256, 256, 0, stream>>>(x, wg, mk, xt, wt);
    k_conv<<<(TOTPIX / 64) * 2, 128, 0, stream>>>(xt, wt, out);
}

// Round 16
// 150.603 us; speedup vs baseline: 1.1183x; 1.1183x over previous
//
#include <hip/hip_runtime.h>
#include <hip/hip_bf16.h>

typedef short short8 __attribute__((ext_vector_type(8)));
typedef float float4v __attribute__((ext_vector_type(4)));

#define NIMG 32
#define CIN 256
#define COUT 256
#define HH 56
#define WW 56
#define HP 58
#define WP 58
#define PIXIMG (HH * WW)          /* 3136 */
#define TOTPIX (NIMG * PIXIMG)    /* 100352 */
#define OUTSTRIDE_N (COUT * PIXIMG)
#define TR_BLOCKS (NIMG * HP * 4) /* 7424 transpose blocks in k_pre */

static constexpr size_t XT_ELEMS = (size_t)NIMG * HP * WP * CIN; // bf16
static constexpr size_t WT_ELEMS = (size_t)9 * COUT * CIN;       // bf16

// fp32 -> bf16 bits, round-to-nearest-even (finite inputs only)
static __device__ __forceinline__ unsigned short f2bf(float f) {
    unsigned int u = __builtin_bit_cast(unsigned int, f);
    u = (u + 0x7fffu + ((u >> 16) & 1u)) >> 16;
    return (unsigned short)u;
}

// async global(16B/lane) -> LDS (wave-uniform base + lane*16)
static __device__ __forceinline__ void gl16(const unsigned short* g, char* l) {
    __builtin_amdgcn_global_load_lds(
        (const __attribute__((address_space(1))) void*)g,
        (__attribute__((address_space(3))) void*)l, 16, 0, 0);
}

// ---------------------------------------------------------------------------
// Merged pre-pass. Blocks [0, TR_BLOCKS): x NCHW fp32 -> x_t[n][h'][w'][ic]
// bf16 (padded, halo zeroed in-kernel). Blocks [TR_BLOCKS, +256):
// wt[tap][oc][ic] = bf16(weight*mask). ~5.6 TB/s ~= 89% achievable HBM:
// at the memory roofline (ideal traffic 158 MB -> 25 us floor).
// ---------------------------------------------------------------------------
__global__ __launch_bounds__(256) void k_pre(const float* __restrict__ x,
                                             const float* __restrict__ wgt,
                                             const float* __restrict__ msk,
                                             unsigned short* __restrict__ xt,
                                             unsigned short* __restrict__ wt) {
    int t = threadIdx.x;
    if (blockIdx.x >= TR_BLOCKS) {
        // ---- prepw part ----
        int g = (blockIdx.x - TR_BLOCKS) * 256 + t; // g = oc*256 + ic
        const float* wp = wgt + (size_t)g * 9;
        const float* mp = msk + (size_t)g * 9;
#pragma unroll
        for (int tap = 0; tap < 9; ++tap)
            wt[(size_t)tap * (COUT * CIN) + g] = f2bf(wp[tap] * mp[tap]);
        return;
    }
    // ---- transpose part ----
    int b   = blockIdx.x;
    int icb = b & 3;
    int hp  = (b >> 2) % HP;    // padded output row 0..57
    int n   = b / (4 * HP);
    unsigned short* rowb = xt + ((size_t)(n * HP + hp) * WP) * CIN + icb * 64;

    if (hp == 0 || hp == HP - 1) {
        for (int idx = t; idx < WP * 8; idx += 256) {
            int wq = idx >> 3, q = idx & 7;
            *(uint4*)(rowb + (size_t)wq * CIN + q * 8) = (uint4){0, 0, 0, 0};
        }
        return;
    }
    int h = hp - 1;
    __shared__ __align__(16) char lds[64 * 128]; // [w 64][ic 64] bf16, swizzled
    int w = t & 63, icl0 = t >> 6;
    if (w < WW) {
        const float* src = x + ((size_t)(n * CIN + icb * 64 + icl0) * HH + h) * WW + w;
#pragma unroll
        for (int j = 0; j < 16; ++j) {
            float v = src[(size_t)(j * 4) * PIXIMG];
            int icl = icl0 + j * 4;
            *(unsigned short*)(lds + w * 128 + ((icl * 2) ^ ((w & 7) << 4))) = f2bf(v);
        }
    }
    __syncthreads();
    int ic4 = t & 15, wr = t >> 4;
    unsigned short* dst = rowb + (size_t)CIN + ic4 * 4; // w'=1 base
#pragma unroll
    for (int p = 0; p < 4; ++p) {
        int w2 = wr + p * 16;
        if (w2 < WW) {
            uint2 v = *(const uint2*)(lds + w2 * 128 + ((ic4 * 8) ^ ((w2 & 7) << 4)));
            *(uint2*)(dst + (size_t)w2 * CIN) = v;
        }
    }
    if (t < 32) { // zero w'=0 and w'=57 columns
        int col = (t >> 4) * (WP - 1);
        *(uint2*)(rowb + (size_t)col * CIN + (t & 15) * 4) = (uint2){0, 0};
    }
}

// ---------------------------------------------------------------------------
// Main conv (champion, FINAL): 9 shifted GEMMs, m97 structure: 128x128 tile,
// 4 waves (2x2), BK=64, SINGLE 32KB A+B buffer, {STAGE; sync; COMP; sync}
// per K-step. Measured 122.6 us = 968 TF = 39% dense peak (3x reproduced).
// PER-STEP LATENCY-BOUND: the vmcnt(0)+barrier drain (~L2 round-trip) stalls
// a whole block; hidden ~3x by co-resident blocks. This configuration is the
// unique point avoiding the >128-unified-VGPR cliff (60 arch + 64 AGPR acc =
// 124), the LDS cap, and keeping 32 MFMA/wave-step.
// Falsified on THIS problem: dbuf 141 (r2) | 8-phase 175/176 (r3/r4) |
// counted-vmcnt BK32 158/160 (r8/r9) | halo-B-reuse 134 (r11: FETCH -66%,
// no gain) | A-direct-from-L2 136 (r13: LDS traffic halved, no gain; VGPR
// 132 > 128 cliff) | 2-wave 6-domain 142 (r15: same cliff).
// Only measured positive lever: waves/CU 8->12 (r2->r5).
// ---------------------------------------------------------------------------
__global__ __launch_bounds__(256, 4) void k_conv(const unsigned short* __restrict__ xt,
                                                 const unsigned short* __restrict__ wt,
                                                 float* __restrict__ out) {
    __shared__ __align__(16) char lds[64 * 132 * 4]; // 33792 B
    // K-loop uses first 32KB: A [128 oc][64 ic] @0, B [128 pix][64 ic] @16384

    const int t    = threadIdx.x;
    const int lane = t & 63;
    const int wid  = t >> 6;
    const int woc  = wid >> 1; // 64-oc half
    const int wpx  = wid & 1;  // 64-pix half

    // XCD-aware chunked swizzle: 1568 blocks = 8 XCDs x 196
    const int b0 = blockIdx.x;
    const int b  = (b0 & 7) * 196 + (b0 >> 3);
    const int ptile = b >> 1;
    const int ocb   = b & 1;

    // ---- staging: wave stages rows [wid*32, +32) of A and B; 4 gl16 each ----
    const int rl  = lane >> 3;                 // row-within-8 at dest
    const int sc  = ((lane & 7) ^ rl) * 8;     // inverse-swizzled src col (elems)
    const unsigned short* aS[4];
    const unsigned short* bS[4];
    char* dA[4];
    char* dB[4];
#pragma unroll
    for (int c = 0; c < 4; ++c) {
        int r = wid * 32 + c * 8 + rl;
        aS[c] = wt + (size_t)(ocb * 128 + r) * CIN + sc;
        int pg  = ptile * 128 + r;
        int n   = pg / PIXIMG;
        int rem = pg - n * PIXIMG;
        int h   = rem / WW, w = rem - h * WW;
        bS[c] = xt + ((size_t)((n * HP + h) * WP + w)) * CIN + sc;
        dA[c] = lds + (wid * 32 + c * 8) * 128;
        dB[c] = lds + 16384 + (wid * 32 + c * 8) * 128;
    }

    // ---- fragment read offsets ----
    const int l15  = lane & 15;
    const int lg   = lane >> 4;
    const int swzf = (lane & 7) << 4;
    int colk[2];
    colk[0] = (lg * 16) ^ swzf;
    colk[1] = (64 + lg * 16) ^ swzf;
    int rowA[4], rowB[4];
#pragma unroll
    for (int i = 0; i < 4; ++i) {
        rowA[i] = (woc * 64 + i * 16 + l15) * 128;
        rowB[i] = 16384 + (wpx * 64 + i * 16 + l15) * 128;
    }

    float4v acc[4][4];
#pragma unroll
    for (int i = 0; i < 4; ++i)
#pragma unroll
        for (int j = 0; j < 4; ++j)
            acc[i][j] = (float4v){0.f, 0.f, 0.f, 0.f};

    // ---- main loop: 36 K-steps, single-buffered (m97 structure) ----
#pragma unroll 1
    for (int s = 0; s < 36; ++s) {
        const int tap = s >> 2;
        const int dh  = (tap * 86) >> 8;
        const int dw  = tap - dh * 3;
        const size_t ao = (size_t)tap * (COUT * CIN) + (size_t)((s & 3) << 6);
        const size_t bo = (size_t)(dh * WP + dw) * CIN + (size_t)((s & 3) << 6);
#pragma unroll
        for (int c = 0; c < 4; ++c) gl16(aS[c] + ao, dA[c]);
#pragma unroll
        for (int c = 0; c < 4; ++c) gl16(bS[c] + bo, dB[c]);
        __syncthreads(); // vmcnt(0) drain + barrier: buffer ready
#pragma unroll
        for (int kk = 0; kk < 2; ++kk) {
            short8 af[4], bfr[4];
#pragma unroll
            for (int i = 0; i < 4; ++i)
                af[i] = *(const short8*)(lds + rowA[i] + colk[kk]);
#pragma unroll
            for (int i = 0; i < 4; ++i)
                bfr[i] = *(const short8*)(lds + rowB[i] + colk[kk]);
#pragma unroll
            for (int oi = 0; oi < 4; ++oi)
#pragma unroll
                for (int pi = 0; pi < 4; ++pi)
                    acc[oi][pi] = __builtin_amdgcn_mfma_f32_16x16x32_bf16(
                        af[oi], bfr[pi], acc[oi][pi], 0, 0, 0);
        }
        __syncthreads(); // reads done before next stage overwrites
    }

    // ---- epilogue: 2 chunks of 64 oc via LDS transpose, coalesced stores ----
    float* ep = (float*)lds; // [64 oc][132] f32, pad kills write conflicts
#pragma unroll 1
    for (int c = 0; c < 2; ++c) {
        if (woc == c) {
#pragma unroll
            for (int oi = 0; oi < 4; ++oi)
#pragma unroll
                for (int pi = 0; pi < 4; ++pi)
#pragma unroll
                    for (int r = 0; r < 4; ++r)
                        ep[(oi * 16 + lg * 4 + r) * 132 +
                           (wpx * 64 + pi * 16 + l15)] = acc[oi][pi][r];
        }
        __syncthreads();
        const int rrow = t >> 5;        // 0..7
        const int rcol = (t & 31) * 4;  // 0..124
        int pg  = ptile * 128 + rcol;
        int n2  = pg / PIXIMG;
        int rem = pg - n2 * PIXIMG;     // 3136%4==0: float4 stays in-image
        float* ob = out + (size_t)n2 * OUTSTRIDE_N +
                    (size_t)(ocb * 128 + c * 64) * PIXIMG + rem;
#pragma unroll
        for (int rd = 0; rd < 8; ++rd) {
            int row = rd * 8 + rrow;    // 0..63
            float4v v = *(const float4v*)&ep[row * 132 + rcol];
            *(float4v*)(ob + (size_t)row * PIXIMG) = v;
        }
        __syncthreads(); // chunk reads done before next chunk's writes
    }
}

// ---------------------------------------------------------------------------
// Fallback (ws too small): direct fp32 conv, slow but correct
// ---------------------------------------------------------------------------
__global__ __launch_bounds__(256) void k_naive(const float* __restrict__ x,
                                               const float* __restrict__ wg,
                                               const float* __restrict__ mk,
                                               float* __restrict__ out, int total) {
    int idx = blockIdx.x * 256 + threadIdx.x;
    if (idx >= total) return;
    int w  = idx % WW;
    int h  = (idx / WW) % HH;
    int oc = (idx / PIXIMG) % COUT;
    int n  = idx / (COUT * PIXIMG);
    float s = 0.f;
    for (int ic = 0; ic < CIN; ++ic) {
        const float* xp = x + (size_t)(n * CIN + ic) * PIXIMG;
        const float* wp = wg + (size_t)(oc * CIN + ic) * 9;
        const float* mp = mk + (size_t)(oc * CIN + ic) * 9;
#pragma unroll
        for (int kh = 0; kh < 3; ++kh) {
            int hy = h + kh - 1;
            if ((unsigned)hy >= HH) continue;
#pragma unroll
            for (int kw = 0; kw < 3; ++kw) {
                int wx = w + kw - 1;
                if ((unsigned)wx >= WW) continue;
                s += xp[hy * WW + wx] * wp[kh * 3 + kw] * mp[kh * 3 + kw];
            }
        }
    }
    out[idx] = s;
}

extern "C" void kernel_launch(void* const* d_in, const int* in_sizes, int n_in,
                              void* d_out, int out_size, void* d_ws, size_t ws_size,
                              hipStream_t stream) {
    const float* x  = (const float*)d_in[0];
    const float* wg = (const float*)d_in[1];
    const float* mk = (const float*)d_in[2];
    float* out = (float*)d_out;

    size_t need = XT_ELEMS * 2 + WT_ELEMS * 2 + 256;
    if (ws_size < need) {
        int total = NIMG * COUT * PIXIMG;
        k_naive<<<(total + 255) / 256, 256, 0, stream>>>(x, wg, mk, out, total);
        return;
    }

    unsigned short* xt = (unsigned short*)d_ws;
    unsigned short* wt = (unsigned short*)((char*)d_ws + XT_ELEMS * 2);

    k_pre<<<TR_BLOCKS + (COUT * CIN) / 256, 256, 0, stream>>>(x, wg, mk, xt, wt);
    k_conv<<<(TOTPIX / 128) * 2, 256, 0, stream>>>(xt, wt, out);
}